// Round 1
// baseline (227.297 us; speedup 1.0000x reference)
//
#include <hip/hip_runtime.h>

#define NB 4
#define SEQ 2048
#define NH 16
#define HD 64
#define DMODEL 1024

typedef short bf16x8 __attribute__((ext_vector_type(8)));
typedef float f32x16 __attribute__((ext_vector_type(16)));

union FragU {
    bf16x8 v;
    uint2 u2[2];
    unsigned short s[8];
};

__device__ __forceinline__ unsigned int f2bf_bits(float x) {
    unsigned int u = __float_as_uint(x);
    return (u + 0x8000u) >> 16;   // round-to-nearest (ties away); unbiased enough for 2% tol
}

__device__ __forceinline__ float silu_f(float s) {
    // silu(s) = s / (1 + exp(-s)); exp via exp2, div via rcp (≈1 ulp each)
    float e = __builtin_amdgcn_exp2f(s * -1.44269504f);
    return s * __builtin_amdgcn_rcpf(1.0f + e);
}

// Block: 256 threads = 4 waves. Each wave computes a 64q x 64d output tile.
// Per iter: stage K[64][64] (natural) and V[64][64] (transposed) as bf16 in LDS,
// compute S^T = K*Q^T (C layout: lane=q col), bias+silu in regs, feed directly
// as A-operand of P*V (k-slot permutation matched by V fragment addressing).
__global__ __launch_bounds__(256, 2)
void paa_kernel(const float* __restrict__ Vg, const float* __restrict__ Kg,
                const float* __restrict__ Qg, const float* __restrict__ RW,
                float* __restrict__ Og)
{
    __shared__ __align__(16) unsigned short KsLds[64 * 68];  // [kc][d], stride 68 (2-way max on frag reads)
    __shared__ __align__(16) unsigned short VtLds[64 * 68];  // [d][kc], stride 68
    __shared__ float btab[128];                              // bias by distance, clamped at 127 (bucket 31 for d>=113)

    const int tid  = threadIdx.x;
    const int lane = tid & 63;
    const int wave = tid >> 6;
    const int half = lane >> 5;
    const int l31  = lane & 31;

    const int bid  = blockIdx.x;
    const int bh   = bid & 63;   // same (b,h) -> same XCD if dispatch is id%8
    const int qt   = bid >> 6;   // 0..7
    const int b    = bh >> 4;
    const int head = bh & 15;

    const int q0w = qt * 256 + wave * 64;

    // ---- bias table (matches reference bucket math in fp32) ----
    if (tid < 128) {
        int rp = tid;
        int bucket;
        if (rp < 16) bucket = rp;
        else {
            int big = 16 + (int)(logf((float)rp * 0.0625f) * 7.6943736f); // 16/ln(8)
            bucket = big < 31 ? big : 31;
        }
        btab[tid] = RW[bucket * NH + head];
    }

    // ---- preload Q fragments (B operand of S^T): qf[u][kf], dd = kf*16 + half*8 + j ----
    FragU qf[2][4];
    {
        const float* qbase = Qg + (size_t)(b * SEQ) * DMODEL + head * HD;
        #pragma unroll
        for (int u = 0; u < 2; ++u) {
            const float* qrow = qbase + (size_t)(q0w + u * 32 + l31) * DMODEL;
            #pragma unroll
            for (int kf = 0; kf < 4; ++kf) {
                int dd = kf * 16 + half * 8;
                float4 x0 = *(const float4*)(qrow + dd);
                float4 x1 = *(const float4*)(qrow + dd + 4);
                FragU f;
                f.s[0] = f2bf_bits(x0.x); f.s[1] = f2bf_bits(x0.y);
                f.s[2] = f2bf_bits(x0.z); f.s[3] = f2bf_bits(x0.w);
                f.s[4] = f2bf_bits(x1.x); f.s[5] = f2bf_bits(x1.y);
                f.s[6] = f2bf_bits(x1.z); f.s[7] = f2bf_bits(x1.w);
                qf[u][kf] = f;
            }
        }
    }

    f32x16 oacc[2][2];
    #pragma unroll
    for (int u = 0; u < 2; ++u)
        #pragma unroll
        for (int n = 0; n < 2; ++n)
            #pragma unroll
            for (int r = 0; r < 16; ++r) oacc[u][n][r] = 0.0f;

    __syncthreads();
    const float bias_d0  = btab[0];    // all d <= 0  -> bucket 0
    const float bias_far = btab[127];  // all d >= 113 -> bucket 31

    const float* kbase = Kg + (size_t)(b * SEQ) * DMODEL + head * HD;
    const float* vbase = Vg + (size_t)(b * SEQ) * DMODEL + head * HD;
    const int kc4 = tid >> 4;  // 0..15 (V staging: 4 kc rows)
    const int d4  = tid & 15;  // 0..15 (V staging: 4 d cols)

    for (int it = 0; it < 32; ++it) {
        const int kcb = it * 64;

        // ---- stage K: fp32 -> bf16, natural [kc][d] ----
        #pragma unroll
        for (int i = 0; i < 4; ++i) {
            int f = tid + i * 256;
            int row = f >> 4;
            int c4  = f & 15;
            float4 x = *(const float4*)(kbase + (size_t)(kcb + row) * DMODEL + c4 * 4);
            uint2 w;
            w.x = f2bf_bits(x.x) | (f2bf_bits(x.y) << 16);
            w.y = f2bf_bits(x.z) | (f2bf_bits(x.w) << 16);
            *(uint2*)&KsLds[row * 68 + c4 * 4] = w;
        }
        // ---- stage V transposed: per-thread 4x4 register transpose, b64 writes ----
        {
            float a[4][4];
            #pragma unroll
            for (int r = 0; r < 4; ++r) {
                float4 x = *(const float4*)(vbase + (size_t)(kcb + kc4 * 4 + r) * DMODEL + d4 * 4);
                a[r][0] = x.x; a[r][1] = x.y; a[r][2] = x.z; a[r][3] = x.w;
            }
            #pragma unroll
            for (int c = 0; c < 4; ++c) {
                uint2 w;
                w.x = f2bf_bits(a[0][c]) | (f2bf_bits(a[1][c]) << 16);
                w.y = f2bf_bits(a[2][c]) | (f2bf_bits(a[3][c]) << 16);
                *(uint2*)&VtLds[(d4 * 4 + c) * 68 + kc4 * 4] = w;
            }
        }
        __syncthreads();

        // ---- S^T = K * Q^T : st[t][u], C layout row=kc_local, col=q_local ----
        f32x16 st[2][2];
        #pragma unroll
        for (int t = 0; t < 2; ++t)
            #pragma unroll
            for (int u = 0; u < 2; ++u)
                #pragma unroll
                for (int r = 0; r < 16; ++r) st[t][u][r] = 0.0f;

        #pragma unroll
        for (int t = 0; t < 2; ++t) {
            #pragma unroll
            for (int kf = 0; kf < 4; ++kf) {
                FragU ka;
                int off = (t * 32 + l31) * 68 + kf * 16 + half * 8;
                ka.u2[0] = *(const uint2*)&KsLds[off];
                ka.u2[1] = *(const uint2*)&KsLds[off + 4];
                #pragma unroll
                for (int u = 0; u < 2; ++u)
                    st[t][u] = __builtin_amdgcn_mfma_f32_32x32x16_bf16(
                        ka.v, qf[u][kf].v, st[t][u], 0, 0, 0);
            }
        }

        // ---- bias + silu -> P fragments (A operand, permuted k-slots) ----
        FragU pf[2][4];
        #pragma unroll
        for (int t = 0; t < 2; ++t) {
            const int kcmin = kcb + t * 32;
            #pragma unroll
            for (int u = 0; u < 2; ++u) {
                const int qminu = q0w + u * 32;
                float vals[16];
                if (qminu + 31 - kcmin <= 0) {              // whole tile d<=0
                    #pragma unroll
                    for (int r = 0; r < 16; ++r) vals[r] = silu_f(st[t][u][r] + bias_d0);
                } else if (qminu - (kcmin + 31) >= 113) {   // whole tile bucket 31
                    #pragma unroll
                    for (int r = 0; r < 16; ++r) vals[r] = silu_f(st[t][u][r] + bias_far);
                } else {                                    // mixed band (~9% of tiles)
                    const int dql = qminu + l31 - kcmin - 4 * half;
                    #pragma unroll
                    for (int r = 0; r < 16; ++r) {
                        int dv = dql - ((r & 3) + 8 * (r >> 2));
                        dv = dv < 0 ? 0 : (dv > 127 ? 127 : dv);
                        vals[r] = silu_f(st[t][u][r] + btab[dv]);
                    }
                }
                #pragma unroll
                for (int r = 0; r < 8; ++r) pf[u][t * 2].s[r]     = f2bf_bits(vals[r]);
                #pragma unroll
                for (int r = 0; r < 8; ++r) pf[u][t * 2 + 1].s[r] = f2bf_bits(vals[r + 8]);
            }
        }

        // ---- O += P * V : V B-fragments address-matched to P's k-slot permutation ----
        // k_hw slot (half,j) of frag f corresponds to kc = 16f + (j&3) + 8*(j>>2) + 4*half
        #pragma unroll
        for (int f = 0; f < 4; ++f) {
            #pragma unroll
            for (int n = 0; n < 2; ++n) {
                FragU vf;
                int off = (n * 32 + l31) * 68 + f * 16 + half * 4;
                vf.u2[0] = *(const uint2*)&VtLds[off];      // kc offsets 4h..4h+3
                vf.u2[1] = *(const uint2*)&VtLds[off + 8];  // kc offsets 4h+8..4h+11
                #pragma unroll
                for (int u = 0; u < 2; ++u)
                    oacc[u][n] = __builtin_amdgcn_mfma_f32_32x32x16_bf16(
                        pf[u][f].v, vf.v, oacc[u][n], 0, 0, 0);
            }
        }
        __syncthreads();
    }

    // ---- store: C layout row=q_local, col=d_local -> coalesced along d ----
    float* obase = Og + (size_t)(b * SEQ) * DMODEL + head * HD;
    #pragma unroll
    for (int u = 0; u < 2; ++u) {
        #pragma unroll
        for (int r = 0; r < 16; ++r) {
            int q = q0w + u * 32 + (r & 3) + 8 * (r >> 2) + 4 * half;
            float* orow = obase + (size_t)q * DMODEL;
            #pragma unroll
            for (int n = 0; n < 2; ++n)
                orow[n * 32 + l31] = oacc[u][n][r];
        }
    }
}

extern "C" void kernel_launch(void* const* d_in, const int* in_sizes, int n_in,
                              void* d_out, int out_size, void* d_ws, size_t ws_size,
                              hipStream_t stream) {
    const float* v  = (const float*)d_in[0];
    const float* k  = (const float*)d_in[1];
    const float* q  = (const float*)d_in[2];
    const float* rw = (const float*)d_in[3];
    float* out = (float*)d_out;
    paa_kernel<<<dim3(512), dim3(256), 0, stream>>>(v, k, q, rw, out);
}